// Round 3
// baseline (308.741 us; speedup 1.0000x reference)
//
#include <hip/hip_runtime.h>
#include <cstddef>

#define NTHREADS 256
#define TROW 8192
#define NROWS 512
#define TILE 1024
#define HALO 256
#define REG 1280           // region length = TILE + HALO
#define CHUNK 5            // REG / NTHREADS
#define KOUT 4             // TILE / NTHREADS
#define PADL 64            // left pad for branch-free window reads
#define FEPS 1e-8f

static_assert(REG == TILE + HALO, "region");
static_assert(CHUNK * NTHREADS == REG, "chunk");
static_assert(KOUT * NTHREADS == TILE, "kout");

__device__ __forceinline__ float rcp_fast(float x) { return __builtin_amdgcn_rcpf(x); }
__device__ __forceinline__ float sqrt_fast(float x) { return __builtin_amdgcn_sqrtf(x); }
__device__ __forceinline__ float pow5(float b) { float b2 = b * b; return b2 * b2 * b; }

__global__ __launch_bounds__(NTHREADS) void feat_kernel(
    const float* __restrict__ close, float* __restrict__ out) {
  // Logical index i in [-PADL, REG) maps to array index PADL+i.
  // Pads emulate front-extension by close[s]: cl[<0]=c0, Qa[i<0]=i*c0, Qs/Qd[<0]=0.
  __shared__ alignas(16) float cl[PADL + REG];
  __shared__ float Qa[PADL + REG + 1];   // prefix of close
  __shared__ float Qs[PADL + REG + 1];   // prefix of (close-mean20)^2
  __shared__ float Qd[PADL + REG + 1];   // prefix of |delta|
  __shared__ float Mm[REG];              // macd
  __shared__ float Ss[REG];              // signal
  __shared__ float sc[64];               // per-phase DISJOINT slices (no reuse hazards)

  const int tid = threadIdx.x;
  const int lane = tid & 63;
  const int wid = tid >> 6;
  const int j = blockIdx.x;   // tile
  const int r = blockIdx.y;   // row
  const int out_start = j * TILE;
  const int s = (j == 0) ? 0 : (out_start - HALO);
  const int ob = out_start - s;                      // 0 or HALO
  const size_t BT = (size_t)NROWS * TROW;
  const size_t rbase = (size_t)r * TROW + (size_t)s;

  // ---- P1: load region (float4; rbase is a multiple of 256 elems) + pads ----
  const float4* rp4 = (const float4*)(close + rbase);
  ((float4*)(cl + PADL))[tid] = rp4[tid];
  if (tid < (REG / 4 - NTHREADS))
    ((float4*)(cl + PADL))[NTHREADS + tid] = rp4[NTHREADS + tid];
  const float c0v = close[rbase];          // broadcast from global, not LDS
  if (tid < PADL) {
    cl[tid] = c0v;
    Qa[tid] = (float)(tid - PADL) * c0v;
    Qs[tid] = 0.f;
    Qd[tid] = 0.f;
  }
  __syncthreads();   // loads AND pads visible to everyone from here on

  // ---- P2: Qa = prefix(close) ----  scratch: sc[0..3]
  {
    const int c0 = tid * CHUNK;
    float v[CHUNK];
    float tot = 0.f;
#pragma unroll
    for (int k = 0; k < CHUNK; ++k) { v[k] = cl[PADL + c0 + k]; tot += v[k]; }
    float x = tot;
#pragma unroll
    for (int off = 1; off < 64; off <<= 1) {
      float y = __shfl_up(x, off, 64);
      if (lane >= off) x += y;
    }
    if (lane == 63) sc[wid] = x;
    __syncthreads();
    float run = x - tot;
    for (int w = 0; w < wid; ++w) run += sc[w];
    if (tid == 0) Qa[PADL] = 0.f;
#pragma unroll
    for (int k = 0; k < CHUNK; ++k) { run += v[k]; Qa[PADL + c0 + k + 1] = run; }
    __syncthreads();
  }

  // ---- P3: dual prefix: Qs = prefix(sq_diff), Qd = prefix(|delta|) ----
  // scratch: sc[8..15]
  {
    const int c0 = tid * CHUNK;
    float a[CHUNK], b[CHUNK];
    float t1 = 0.f, t2 = 0.f;
#pragma unroll
    for (int k = 0; k < CHUNK; ++k) {
      const int p = PADL + c0 + k;
      const float c = cl[p];
      const float m20 = (Qa[p + 1] - Qa[p - 19]) * 0.05f;
      const float d = c - m20;
      a[k] = d * d; t1 += a[k];
      b[k] = fabsf(c - cl[p - 1]); t2 += b[k];   // pad makes delta[0]==0
    }
    float x1 = t1, x2 = t2;
#pragma unroll
    for (int off = 1; off < 64; off <<= 1) {
      float y1 = __shfl_up(x1, off, 64);
      float y2 = __shfl_up(x2, off, 64);
      if (lane >= off) { x1 += y1; x2 += y2; }
    }
    if (lane == 63) { sc[8 + wid * 2] = x1; sc[8 + wid * 2 + 1] = x2; }
    __syncthreads();
    float r1 = x1 - t1, r2 = x2 - t2;
    for (int w = 0; w < wid; ++w) { r1 += sc[8 + w * 2]; r2 += sc[8 + w * 2 + 1]; }
    if (tid == 0) { Qs[PADL] = 0.f; Qd[PADL] = 0.f; }
#pragma unroll
    for (int k = 0; k < CHUNK; ++k) {
      r1 += a[k]; Qs[PADL + c0 + k + 1] = r1;
      r2 += b[k]; Qd[PADL + c0 + k + 1] = r2;
    }
    __syncthreads();
  }

  // ---- P4: dual EMA (12, 26) scan -> Mm (macd) ----  scratch: sc[16..31]
  {
    const float a12 = 2.f / 13.f, b12 = 11.f / 13.f;
    const float a26 = 2.f / 27.f, b26 = 25.f / 27.f;
    const int c0 = tid * CHUNK;
    float v[CHUNK];
#pragma unroll
    for (int k = 0; k < CHUNK; ++k) v[k] = cl[PADL + c0 + k];
    float y1 = 0.f, y2 = 0.f;
#pragma unroll
    for (int k = 0; k < CHUNK; ++k) {
      const float x = v[k];
      if (c0 + k == 0) { y1 = x; y2 = x; }
      else { y1 = fmaf(b12, y1, a12 * x); y2 = fmaf(b26, y2, a26 * x); }
    }
    float A1 = (tid == 0) ? 0.f : pow5(b12);
    float A2 = (tid == 0) ? 0.f : pow5(b26);
    float B1 = y1, B2 = y2;
#pragma unroll
    for (int off = 1; off < 64; off <<= 1) {
      const float pA1 = __shfl_up(A1, off, 64), pB1 = __shfl_up(B1, off, 64);
      const float pA2 = __shfl_up(A2, off, 64), pB2 = __shfl_up(B2, off, 64);
      if (lane >= off) {
        B1 = fmaf(A1, pB1, B1); A1 *= pA1;
        B2 = fmaf(A2, pB2, B2); A2 *= pA2;
      }
    }
    float eA1 = __shfl_up(A1, 1, 64), eB1 = __shfl_up(B1, 1, 64);
    float eA2 = __shfl_up(A2, 1, 64), eB2 = __shfl_up(B2, 1, 64);
    if (lane == 0) { eA1 = 1.f; eB1 = 0.f; eA2 = 1.f; eB2 = 0.f; }
    if (lane == 63) {
      sc[16 + wid * 4 + 0] = A1; sc[16 + wid * 4 + 1] = B1;
      sc[16 + wid * 4 + 2] = A2; sc[16 + wid * 4 + 3] = B2;
    }
    __syncthreads();
    float cB1 = 0.f, cB2 = 0.f;
    for (int w = 0; w < wid; ++w) {
      cB1 = fmaf(sc[16 + w * 4 + 0], cB1, sc[16 + w * 4 + 1]);
      cB2 = fmaf(sc[16 + w * 4 + 2], cB2, sc[16 + w * 4 + 3]);
    }
    y1 = fmaf(eA1, cB1, eB1);
    y2 = fmaf(eA2, cB2, eB2);
#pragma unroll
    for (int k = 0; k < CHUNK; ++k) {
      const float x = v[k];
      if (c0 + k == 0) { y1 = x; y2 = x; }
      else { y1 = fmaf(b12, y1, a12 * x); y2 = fmaf(b26, y2, a26 * x); }
      Mm[c0 + k] = y1 - y2;
    }
    __syncthreads();
  }

  // ---- P5: signal = ema9(macd) -> Ss ----  scratch: sc[40..47]
  {
    const float a9 = 0.2f, b9 = 0.8f;
    const int c0 = tid * CHUNK;
    float v[CHUNK];
#pragma unroll
    for (int k = 0; k < CHUNK; ++k) v[k] = Mm[c0 + k];
    float y = 0.f;
#pragma unroll
    for (int k = 0; k < CHUNK; ++k) {
      const float x = v[k];
      if (c0 + k == 0) y = x;
      else y = fmaf(b9, y, a9 * x);
    }
    float A = (tid == 0) ? 0.f : pow5(b9);
    float Bv = y;
#pragma unroll
    for (int off = 1; off < 64; off <<= 1) {
      const float pA = __shfl_up(A, off, 64), pB = __shfl_up(Bv, off, 64);
      if (lane >= off) { Bv = fmaf(A, pB, Bv); A *= pA; }
    }
    float eA = __shfl_up(A, 1, 64), eB = __shfl_up(Bv, 1, 64);
    if (lane == 0) { eA = 1.f; eB = 0.f; }
    if (lane == 63) { sc[40 + wid * 2] = A; sc[40 + wid * 2 + 1] = Bv; }
    __syncthreads();
    float cB = 0.f;
    for (int w = 0; w < wid; ++w) cB = fmaf(sc[40 + w * 2], cB, sc[40 + w * 2 + 1]);
    y = fmaf(eA, cB, eB);
#pragma unroll
    for (int k = 0; k < CHUNK; ++k) {
      const float x = v[k];
      if (c0 + k == 0) y = x;
      else y = fmaf(b9, y, a9 * x);
      Ss[c0 + k] = y;
    }
    __syncthreads();
  }

  // ---- P6: single output phase — ALL stores after the last barrier ----
#pragma unroll
  for (int k = 0; k < KOUT; ++k) {
    const int i = ob + tid + k * NTHREADS;
    const int p = PADL + i;
    float* o = out + (rbase + (size_t)i);
    const float c = cl[p];
    const float q1 = Qa[p + 1];
    const float ma5  = (q1 - Qa[p - 4])  * 0.2f;
    const float ma10 = (q1 - Qa[p - 9])  * 0.1f;
    const float ma20 = (q1 - Qa[p - 19]) * 0.05f;
    const float ma50 = (q1 - Qa[p - 49]) * 0.02f;
    o[0]        = ma5;
    o[1 * BT]   = c * rcp_fast(ma5 + FEPS);
    o[2 * BT]   = ma10;
    o[3 * BT]   = c * rcp_fast(ma10 + FEPS);
    o[4 * BT]   = ma20;
    o[5 * BT]   = c * rcp_fast(ma20 + FEPS);
    o[6 * BT]   = ma50;
    o[7 * BT]   = c * rcp_fast(ma50 + FEPS);
    const float sabs = Qd[p + 1] - Qd[p - 13];
    const float sdel = c - cl[p - 14];
    // rsi = 100*g/(g+l+eps) = 100*(sabs+sdel) / (2*sabs + 28*eps)
    o[8 * BT]   = 100.f * (sabs + sdel) * rcp_fast(2.f * sabs + 28.f * FEPS);
    const float m = Mm[i], sg = Ss[i];
    o[9 * BT]   = m;
    o[10 * BT]  = sg;
    o[11 * BT]  = m - sg;
    const float var = fmaxf((Qs[p + 1] - Qs[p - 19]) * 0.05f, 0.f);
    const float sd2 = 2.f * sqrt_fast(var + FEPS);
    const float up = ma20 + sd2, lo = ma20 - sd2;
    o[12 * BT]  = up;
    o[13 * BT]  = ma20;
    o[14 * BT]  = lo;
    o[15 * BT]  = (c - lo) * rcp_fast(up - lo + FEPS);
    o[16 * BT]  = sabs * (1.f / 14.f);
  }
}

extern "C" void kernel_launch(void* const* d_in, const int* in_sizes, int n_in,
                              void* d_out, int out_size, void* d_ws, size_t ws_size,
                              hipStream_t stream) {
  (void)in_sizes; (void)n_in; (void)out_size; (void)d_ws; (void)ws_size;
  const float* close = (const float*)d_in[0];  // d_in[1] = volume (unused)
  float* out = (float*)d_out;
  dim3 grid(TROW / TILE, NROWS, 1);
  feat_kernel<<<grid, dim3(NTHREADS, 1, 1), 0, stream>>>(close, out);
}